// Round 5
// baseline (1241.191 us; speedup 1.0000x reference)
//
#include <hip/hip_runtime.h>
#include <math.h>

#define BATCH 1024
#define HID 256
#define W3 768
#define SLOT (BATCH * HID)

typedef __bf16 bf16_t;
typedef __bf16 bf16x8 __attribute__((ext_vector_type(8)));
typedef __bf16 bf16x4 __attribute__((ext_vector_type(4)));
typedef float f32x4 __attribute__((ext_vector_type(4)));

__device__ inline bf16x8 cvt8(const float4 a, const float4 b) {
    bf16x8 r;
    r[0] = (bf16_t)a.x; r[1] = (bf16_t)a.y; r[2] = (bf16_t)a.z; r[3] = (bf16_t)a.w;
    r[4] = (bf16_t)b.x; r[5] = (bf16_t)b.y; r[6] = (bf16_t)b.z; r[7] = (bf16_t)b.w;
    return r;
}
__device__ inline bf16x4 cvt4(const float4 a) {
    bf16x4 r;
    r[0] = (bf16_t)a.x; r[1] = (bf16_t)a.y; r[2] = (bf16_t)a.z; r[3] = (bf16_t)a.w;
    return r;
}

// ---------- generic 128x128 tile GEMM core (k-contiguous operands) ----------
template<bool ATOMIC>
__device__ __forceinline__ void proj_core(
        const float* __restrict__ src, const float* __restrict__ W, int koff,
        const float* __restrict__ bias, float* __restrict__ out,
        bf16_t (*Asm)[40], bf16_t (*Bsm)[40]) {
    const int t = threadIdx.x;
    const int lane = t & 63, wid = t >> 6;
    const int wm = wid & 1, wn = wid >> 1;
    const int ln = lane & 15, lh = lane >> 4;
    const int b0 = blockIdx.x * 128, n0 = blockIdx.y * 128;
    const int sr = t >> 1, sq = (t & 1) * 16;
    const float* arow = src + (size_t)(b0 + sr) * HID + sq;
    const float* wrow = W + (size_t)(n0 + sr) * W3 + koff + sq;
    f32x4 acc[4][4] = {};
    for (int kb = 0; kb < 8; ++kb) {
        const float4 a0 = *(const float4*)(arow + kb * 32);
        const float4 a1 = *(const float4*)(arow + kb * 32 + 4);
        const float4 a2 = *(const float4*)(arow + kb * 32 + 8);
        const float4 a3 = *(const float4*)(arow + kb * 32 + 12);
        const float4 w0 = *(const float4*)(wrow + kb * 32);
        const float4 w1 = *(const float4*)(wrow + kb * 32 + 4);
        const float4 w2 = *(const float4*)(wrow + kb * 32 + 8);
        const float4 w3 = *(const float4*)(wrow + kb * 32 + 12);
        const bf16x8 av0 = cvt8(a0, a1), av1 = cvt8(a2, a3);
        const bf16x8 bv0 = cvt8(w0, w1), bv1 = cvt8(w2, w3);
        __syncthreads();
        *(bf16x8*)&Asm[sr][sq] = av0;
        *(bf16x8*)&Asm[sr][sq + 8] = av1;
        *(bf16x8*)&Bsm[sr][sq] = bv0;
        *(bf16x8*)&Bsm[sr][sq + 8] = bv1;
        __syncthreads();
        bf16x8 af[4], bfv[4];
        #pragma unroll
        for (int mf = 0; mf < 4; ++mf)
            af[mf] = *(const bf16x8*)&Asm[wm * 64 + mf * 16 + ln][lh * 8];
        #pragma unroll
        for (int nf = 0; nf < 4; ++nf)
            bfv[nf] = *(const bf16x8*)&Bsm[wn * 64 + nf * 16 + ln][lh * 8];
        #pragma unroll
        for (int mf = 0; mf < 4; ++mf)
            #pragma unroll
            for (int nf = 0; nf < 4; ++nf)
                acc[mf][nf] = __builtin_amdgcn_mfma_f32_16x16x32_bf16(
                    af[mf], bfv[nf], acc[mf][nf], 0, 0, 0);
    }
    #pragma unroll
    for (int nf = 0; nf < 4; ++nf) {
        const int n = n0 + wn * 64 + nf * 16 + ln;
        const float bn = ATOMIC ? 0.f : bias[n];
        #pragma unroll
        for (int mf = 0; mf < 4; ++mf)
            #pragma unroll
            for (int r = 0; r < 4; ++r) {
                const int b = b0 + wm * 64 + mf * 16 + lh * 4 + r;
                if (ATOMIC)
                    unsafeAtomicAdd(out + (size_t)b * HID + n, acc[mf][nf][r]);
                else
                    out[(size_t)b * HID + n] = acc[mf][nf][r] + bn;
            }
    }
}

// P1/P3: ph_base[k] = grid_h[k]@Wprev_h.T + b_hp ; pc_base likewise. z=2k+hc.
__global__ __launch_bounds__(256) void baseproj_kernel(
        const float* __restrict__ gridh, const float* __restrict__ gridc,
        const float* __restrict__ Whp, const float* __restrict__ Wcp,
        const float* __restrict__ bhp, const float* __restrict__ bcp,
        float* __restrict__ phb, float* __restrict__ pcb) {
    __shared__ bf16_t As[128][40];
    __shared__ bf16_t Bs[128][40];
    const int z = blockIdx.z, k = z >> 1, hc = z & 1;
    const float* src = (hc ? gridc : gridh) + (size_t)k * SLOT;
    const float* W = (hc ? Wcp : Whp) + (size_t)k * HID * W3;
    const float* bias = (hc ? bcp : bhp) + (size_t)k * HID;
    float* out = (hc ? pcb : phb) + (size_t)k * SLOT;
    proj_core<false>(src, W, 512, bias, out, As, Bs);
}

// P2: gates_base[k][b][c'] (fp32, cell layout c' = ub*128 + g*32 + du)
//  = ph_base[k]@Whh.T + x*Wih + bih + bhh
__global__ __launch_bounds__(256) void gatesbase_kernel(
        const float* __restrict__ phb, const float* __restrict__ Whh,
        const float* __restrict__ Wih, const float* __restrict__ bih,
        const float* __restrict__ bhh, const float* __restrict__ x,
        float* __restrict__ gbase) {
    __shared__ bf16_t As[128][40];
    __shared__ bf16_t Bs[128][40];
    const int k = blockIdx.z;
    const int t = threadIdx.x;
    const int lane = t & 63, wid = t >> 6;
    const int wm = wid & 1, wn = wid >> 1;
    const int ln = lane & 15, lh = lane >> 4;
    const int b0 = blockIdx.x * 128;
    const int ub = blockIdx.y, u0 = ub * 32;
    const int sr = t >> 1, sq = (t & 1) * 16;
    const float* arow = phb + (size_t)k * SLOT + (size_t)(b0 + sr) * HID + sq;
    const int g_r = sr >> 5, du_r = sr & 31;
    const float* wrow = Whh + (size_t)k * 4 * HID * HID
                        + (size_t)(g_r * HID + u0 + du_r) * HID + sq;
    f32x4 acc[4][4] = {};
    for (int kb = 0; kb < 8; ++kb) {
        const float4 a0 = *(const float4*)(arow + kb * 32);
        const float4 a1 = *(const float4*)(arow + kb * 32 + 4);
        const float4 a2 = *(const float4*)(arow + kb * 32 + 8);
        const float4 a3 = *(const float4*)(arow + kb * 32 + 12);
        const float4 w0 = *(const float4*)(wrow + kb * 32);
        const float4 w1 = *(const float4*)(wrow + kb * 32 + 4);
        const float4 w2 = *(const float4*)(wrow + kb * 32 + 8);
        const float4 w3 = *(const float4*)(wrow + kb * 32 + 12);
        const bf16x8 av0 = cvt8(a0, a1), av1 = cvt8(a2, a3);
        const bf16x8 bv0 = cvt8(w0, w1), bv1 = cvt8(w2, w3);
        __syncthreads();
        *(bf16x8*)&As[sr][sq] = av0;
        *(bf16x8*)&As[sr][sq + 8] = av1;
        *(bf16x8*)&Bs[sr][sq] = bv0;
        *(bf16x8*)&Bs[sr][sq + 8] = bv1;
        __syncthreads();
        bf16x8 af[4], bfr[4];
        #pragma unroll
        for (int mf = 0; mf < 4; ++mf)
            af[mf] = *(const bf16x8*)&As[wm * 64 + mf * 16 + ln][lh * 8];
        #pragma unroll
        for (int g = 0; g < 4; ++g)
            bfr[g] = *(const bf16x8*)&Bs[g * 32 + wn * 16 + ln][lh * 8];
        #pragma unroll
        for (int mf = 0; mf < 4; ++mf)
            #pragma unroll
            for (int g = 0; g < 4; ++g)
                acc[mf][g] = __builtin_amdgcn_mfma_f32_16x16x32_bf16(
                    af[mf], bfr[g], acc[mf][g], 0, 0, 0);
    }
    const int u = u0 + wn * 16 + ln;
    float wih[4], bb[4];
    #pragma unroll
    for (int g = 0; g < 4; ++g) {
        const int n4 = g * HID + u;
        wih[g] = Wih[(size_t)k * 4 * HID + n4];
        bb[g] = bih[(size_t)k * 4 * HID + n4] + bhh[(size_t)k * 4 * HID + n4];
    }
    float* orow = gbase + (size_t)k * BATCH * 1024;
    #pragma unroll
    for (int mf = 0; mf < 4; ++mf)
        #pragma unroll
        for (int r = 0; r < 4; ++r) {
            const int b = b0 + wm * 64 + mf * 16 + lh * 4 + r;
            const float xv = x[(size_t)b * 81 + k];
            #pragma unroll
            for (int g = 0; g < 4; ++g)
                orow[(size_t)b * 1024 + ub * 128 + g * 32 + wn * 16 + ln] =
                    acc[mf][g][r] + xv * wih[g] + bb[g],
                (void)0;
            // note: 4 scalar stores per (mf,r), one per gate
            #pragma unroll
            for (int g = 1; g < 4; ++g) { } // (loop above already stored all)
        }
}

// P4: CC[k][c'][m'] (bf16), c' = ub*128+g*32+du (cell layout, 1024 rows),
// m' in [0,512) maps to W_hp cols 0..511 (left|up).
// CC[n][m] = sum_u Whh[n][u] * W_hp[u][m]
__global__ __launch_bounds__(256) void compose_kernel(
        const float* __restrict__ Whh, const float* __restrict__ Whp,
        bf16_t* __restrict__ CC) {
    __shared__ bf16_t As[128][40];
    __shared__ bf16_t Bs[128][40];
    const int k = blockIdx.z;
    const int t = threadIdx.x;
    const int lane = t & 63, wid = t >> 6;
    const int wm = wid & 1, wn = wid >> 1;
    const int ln = lane & 15, lh = lane >> 4;
    const int m0 = blockIdx.x * 128;   // 0..3
    const int by = blockIdx.y;         // 0..7 (ub)
    const int sr = t >> 1, sq = (t & 1) * 16;
    const int g_r = sr >> 5, du_r = sr & 31;
    const float* arow = Whh + (size_t)k * 4 * HID * HID
                        + (size_t)(g_r * HID + by * 32 + du_r) * HID + sq;
    const float* wbase = Whp + (size_t)k * HID * W3;
    const int uu = t >> 3, mm0 = (t & 7) * 16;
    f32x4 acc[4][4] = {};
    for (int kb = 0; kb < 8; ++kb) {
        const float4 a0 = *(const float4*)(arow + kb * 32);
        const float4 a1 = *(const float4*)(arow + kb * 32 + 4);
        const float4 a2 = *(const float4*)(arow + kb * 32 + 8);
        const float4 a3 = *(const float4*)(arow + kb * 32 + 12);
        const float* bsrc = wbase + (size_t)(kb * 32 + uu) * W3 + m0 + mm0;
        const float4 v0 = *(const float4*)(bsrc);
        const float4 v1 = *(const float4*)(bsrc + 4);
        const float4 v2 = *(const float4*)(bsrc + 8);
        const float4 v3 = *(const float4*)(bsrc + 12);
        const bf16x8 av0 = cvt8(a0, a1), av1 = cvt8(a2, a3);
        const bf16x4 bq[4] = { cvt4(v0), cvt4(v1), cvt4(v2), cvt4(v3) };
        __syncthreads();
        *(bf16x8*)&As[sr][sq] = av0;
        *(bf16x8*)&As[sr][sq + 8] = av1;
        #pragma unroll
        for (int q = 0; q < 4; ++q)
            #pragma unroll
            for (int e = 0; e < 4; ++e)
                Bs[mm0 + q * 4 + e][uu] = bq[q][e];
        __syncthreads();
        bf16x8 af[4], bf[4];
        #pragma unroll
        for (int mf = 0; mf < 4; ++mf)
            af[mf] = *(const bf16x8*)&As[wm * 64 + mf * 16 + ln][lh * 8];
        #pragma unroll
        for (int nf = 0; nf < 4; ++nf)
            bf[nf] = *(const bf16x8*)&Bs[wn * 64 + nf * 16 + ln][lh * 8];
        #pragma unroll
        for (int mf = 0; mf < 4; ++mf)
            #pragma unroll
            for (int nf = 0; nf < 4; ++nf)
                acc[mf][nf] = __builtin_amdgcn_mfma_f32_16x16x32_bf16(
                    af[mf], bf[nf], acc[mf][nf], 0, 0, 0);
    }
    bf16_t* out = CC + (size_t)k * 1024 * 512;
    #pragma unroll
    for (int nf = 0; nf < 4; ++nf) {
        const int m = m0 + wn * 64 + nf * 16 + ln;
        #pragma unroll
        for (int mf = 0; mf < 4; ++mf)
            #pragma unroll
            for (int r = 0; r < 4; ++r) {
                const int c = by * 128 + wm * 64 + mf * 16 + lh * 4 + r;
                out[(size_t)c * 512 + m] = (bf16_t)acc[mf][nf][r];
            }
    }
}

// ---------- serial wavefront: one fused launch per diagonal ----------
struct FusedDesc {
    const float* hl; const float* cl;     // left h/c (null -> zeros)
    const float* hu; const float* cu;     // up h/c (null -> zeros)
    const float* gb;                      // gates_base[k] fp32 [B][1024] cell layout
    const float* pcb;                     // pc_base[k]  fp32 [B][256]
    const bf16_t* cc;                     // CC[k] bf16 [1024][512]
    const float* wcp;                     // W_cp[k] [256][768]
    float* gh; float* gc;
};
struct FusedBatchArgs { FusedDesc d[9]; };

__global__ __launch_bounds__(256) void fused_kernel(FusedBatchArgs args) {
    const FusedDesc fd = args.d[blockIdx.z];
    __shared__ bf16_t A1[128][40];   // h_cat tile
    __shared__ bf16_t A2[128][40];   // c_cat tile
    __shared__ bf16_t B1[128][40];   // CC tile
    __shared__ bf16_t B2[32][40];    // W_cp tile
    const int t = threadIdx.x;
    const int lane = t & 63, wid = t >> 6;
    const int wm = wid & 1, wn = wid >> 1;
    const int ln = lane & 15, lh = lane >> 4;
    const int b0 = blockIdx.x * 128;
    const int by = blockIdx.y, u0 = by * 32;
    const int sr = t >> 1, sq = (t & 1) * 16;
    const int du2 = t >> 3, kk4 = (t & 7) * 4;

    const float* hs[2]; const float* cs[2]; int ko[2]; int ns = 0;
    if (fd.hl) { hs[ns] = fd.hl; cs[ns] = fd.cl; ko[ns] = 0;   ++ns; }
    if (fd.hu) { hs[ns] = fd.hu; cs[ns] = fd.cu; ko[ns] = 256; ++ns; }

    f32x4 accg[4][4] = {};
    f32x4 accp[4] = {};

    for (int s = 0; s < ns; ++s) {
        const float* ha = hs[s] + (size_t)(b0 + sr) * HID + sq;
        const float* ca = cs[s] + (size_t)(b0 + sr) * HID + sq;
        const bf16_t* b1r = fd.cc + (size_t)(by * 128 + sr) * 512 + ko[s] + sq;
        const float* b2r = fd.wcp + (size_t)(u0 + du2) * W3 + ko[s] + kk4;
        for (int kb = 0; kb < 8; ++kb) {
            const float4 h0 = *(const float4*)(ha + kb * 32);
            const float4 h1 = *(const float4*)(ha + kb * 32 + 4);
            const float4 h2 = *(const float4*)(ha + kb * 32 + 8);
            const float4 h3 = *(const float4*)(ha + kb * 32 + 12);
            const float4 c0 = *(const float4*)(ca + kb * 32);
            const float4 c1 = *(const float4*)(ca + kb * 32 + 4);
            const float4 c2 = *(const float4*)(ca + kb * 32 + 8);
            const float4 c3 = *(const float4*)(ca + kb * 32 + 12);
            const bf16x8 w0 = *(const bf16x8*)(b1r + kb * 32);
            const bf16x8 w1 = *(const bf16x8*)(b1r + kb * 32 + 8);
            const float4 p0 = *(const float4*)(b2r + kb * 32);
            const bf16x8 hv0 = cvt8(h0, h1), hv1 = cvt8(h2, h3);
            const bf16x8 cv0 = cvt8(c0, c1), cv1 = cvt8(c2, c3);
            const bf16x4 pv = cvt4(p0);
            __syncthreads();
            *(bf16x8*)&A1[sr][sq] = hv0;
            *(bf16x8*)&A1[sr][sq + 8] = hv1;
            *(bf16x8*)&A2[sr][sq] = cv0;
            *(bf16x8*)&A2[sr][sq + 8] = cv1;
            *(bf16x8*)&B1[sr][sq] = w0;
            *(bf16x8*)&B1[sr][sq + 8] = w1;
            *(bf16x4*)&B2[du2][kk4] = pv;
            __syncthreads();
            bf16x8 af1[4], bf1[4], af2[4], bf2;
            #pragma unroll
            for (int mf = 0; mf < 4; ++mf) {
                af1[mf] = *(const bf16x8*)&A1[wm * 64 + mf * 16 + ln][lh * 8];
                af2[mf] = *(const bf16x8*)&A2[wm * 64 + mf * 16 + ln][lh * 8];
            }
            #pragma unroll
            for (int g = 0; g < 4; ++g)
                bf1[g] = *(const bf16x8*)&B1[g * 32 + wn * 16 + ln][lh * 8];
            bf2 = *(const bf16x8*)&B2[wn * 16 + ln][lh * 8];
            #pragma unroll
            for (int mf = 0; mf < 4; ++mf) {
                #pragma unroll
                for (int g = 0; g < 4; ++g)
                    accg[mf][g] = __builtin_amdgcn_mfma_f32_16x16x32_bf16(
                        af1[mf], bf1[g], accg[mf][g], 0, 0, 0);
                accp[mf] = __builtin_amdgcn_mfma_f32_16x16x32_bf16(
                    af2[mf], bf2, accp[mf], 0, 0, 0);
            }
        }
    }

    const int u = u0 + wn * 16 + ln;
    #pragma unroll
    for (int mf = 0; mf < 4; ++mf)
        #pragma unroll
        for (int r = 0; r < 4; ++r) {
            const int b = b0 + wm * 64 + mf * 16 + lh * 4 + r;
            const float* gbr = fd.gb + (size_t)b * 1024 + by * 128 + wn * 16 + ln;
            const float gi = accg[mf][0][r] + gbr[0];
            const float gf = accg[mf][1][r] + gbr[32];
            const float gg = accg[mf][2][r] + gbr[64];
            const float go = accg[mf][3][r] + gbr[96];
            const float pc = accp[mf][r] + fd.pcb[(size_t)b * HID + u];
            const float i_ = 1.f / (1.f + expf(-gi));
            const float f_ = 1.f / (1.f + expf(-gf));
            const float o_ = 1.f / (1.f + expf(-go));
            const float g_ = tanhf(gg);
            const float cn = f_ * pc + i_ * g_;
            const float hn = o_ * tanhf(cn);
            fd.gh[(size_t)b * HID + u] = hn;
            fd.gc[(size_t)b * HID + u] = cn;
        }
}

// ---------- fallback kernels (round-4 path) ----------
struct SegDesc { const float* src; const float* W; const float* bias; float* out; int koff; };
struct SegArgs { SegDesc d[36]; };

__global__ __launch_bounds__(256) void projseg_kernel(SegArgs a) {
    __shared__ bf16_t As[128][40];
    __shared__ bf16_t Bs[128][40];
    const SegDesc d = a.d[blockIdx.z];
    if (d.bias) proj_core<false>(d.src, d.W, d.koff, d.bias, d.out, As, Bs);
    else        proj_core<true>(d.src, d.W, d.koff, nullptr, d.out, As, Bs);
}

struct CellDesc {
    const float* ph; const float* pc;
    const float* Whh; const float* Wih; const float* bih; const float* bhh;
    const float* xcol;
    float* gh; float* gc;
};
struct CellBatchArgs { CellDesc d[9]; };

__global__ __launch_bounds__(256) void cell_kernel(CellBatchArgs args) {
    const CellDesc cd = args.d[blockIdx.z];
    __shared__ bf16_t Psm[128][40];
    __shared__ bf16_t Wsm[128][40];
    const int t = threadIdx.x;
    const int lane = t & 63, wid = t >> 6;
    const int wm = wid & 1, wn = wid >> 1;
    const int ln = lane & 15, lh = lane >> 4;
    const int b0 = blockIdx.x * 128;
    const int u0 = blockIdx.y * 32;
    const int sr = t >> 1, sq = (t & 1) * 16;
    const float* prow = cd.ph + (size_t)(b0 + sr) * HID + sq;
    const int cg = sr >> 5, cdu = sr & 31;
    const float* wrow = cd.Whh + (size_t)(cg * HID + u0 + cdu) * HID + sq;
    f32x4 acc[4][4] = {};
    for (int kb = 0; kb < 8; ++kb) {
        const float4 p0 = *(const float4*)(prow + kb * 32);
        const float4 p1 = *(const float4*)(prow + kb * 32 + 4);
        const float4 p2 = *(const float4*)(prow + kb * 32 + 8);
        const float4 p3 = *(const float4*)(prow + kb * 32 + 12);
        const float4 w0 = *(const float4*)(wrow + kb * 32);
        const float4 w1 = *(const float4*)(wrow + kb * 32 + 4);
        const float4 w2 = *(const float4*)(wrow + kb * 32 + 8);
        const float4 w3 = *(const float4*)(wrow + kb * 32 + 12);
        const bf16x8 pv0 = cvt8(p0, p1), pv1 = cvt8(p2, p3);
        const bf16x8 wv0 = cvt8(w0, w1), wv1 = cvt8(w2, w3);
        __syncthreads();
        *(bf16x8*)&Psm[sr][sq] = pv0;
        *(bf16x8*)&Psm[sr][sq + 8] = pv1;
        *(bf16x8*)&Wsm[sr][sq] = wv0;
        *(bf16x8*)&Wsm[sr][sq + 8] = wv1;
        __syncthreads();
        bf16x8 af[4], bfr[4];
        #pragma unroll
        for (int mf = 0; mf < 4; ++mf)
            af[mf] = *(const bf16x8*)&Psm[wm * 64 + mf * 16 + ln][lh * 8];
        #pragma unroll
        for (int g = 0; g < 4; ++g)
            bfr[g] = *(const bf16x8*)&Wsm[g * 32 + wn * 16 + ln][lh * 8];
        #pragma unroll
        for (int mf = 0; mf < 4; ++mf)
            #pragma unroll
            for (int g = 0; g < 4; ++g)
                acc[mf][g] = __builtin_amdgcn_mfma_f32_16x16x32_bf16(
                    af[mf], bfr[g], acc[mf][g], 0, 0, 0);
    }
    const int u = u0 + wn * 16 + ln;
    float wih[4], bsum[4];
    #pragma unroll
    for (int g = 0; g < 4; ++g) {
        const int n = g * HID + u;
        wih[g] = cd.Wih[n];
        bsum[g] = cd.bih[n] + cd.bhh[n];
    }
    #pragma unroll
    for (int mf = 0; mf < 4; ++mf)
        #pragma unroll
        for (int r = 0; r < 4; ++r) {
            const int b = b0 + wm * 64 + mf * 16 + lh * 4 + r;
            const float xv = cd.xcol[(size_t)b * 81];
            const float gi = acc[mf][0][r] + xv * wih[0] + bsum[0];
            const float gf = acc[mf][1][r] + xv * wih[1] + bsum[1];
            const float gg = acc[mf][2][r] + xv * wih[2] + bsum[2];
            const float go = acc[mf][3][r] + xv * wih[3] + bsum[3];
            const float i_ = 1.f / (1.f + expf(-gi));
            const float f_ = 1.f / (1.f + expf(-gf));
            const float o_ = 1.f / (1.f + expf(-go));
            const float g_ = tanhf(gg);
            const float c0 = cd.pc[(size_t)b * HID + u];
            const float cn = f_ * c0 + i_ * g_;
            const float hn = o_ * tanhf(cn);
            cd.gh[(size_t)b * HID + u] = hn;
            cd.gc[(size_t)b * HID + u] = cn;
        }
}

__global__ __launch_bounds__(256) void final_kernel(
        const float* __restrict__ gh88, const float* __restrict__ gc88,
        const float* __restrict__ Wout, const float* __restrict__ bout,
        float* __restrict__ out, float* __restrict__ fh, float* __restrict__ fc) {
    const int tid = blockIdx.x * blockDim.x + threadIdx.x;
    const int nth = gridDim.x * blockDim.x;
    for (int idx = tid; idx < BATCH * HID; idx += nth) {
        fh[idx] = gh88[idx];
        fc[idx] = gc88[idx];
    }
    if (tid < BATCH) {
        float s = bout[0];
        for (int k = 0; k < HID; ++k) s += gh88[(size_t)tid * HID + k] * Wout[k];
        s = fmaxf(s, 0.f);
        out[tid] = 1.f / (1.f + expf(-s));
    }
}

extern "C" void kernel_launch(void* const* d_in, const int* in_sizes, int n_in,
                              void* d_out, int out_size, void* d_ws, size_t ws_size,
                              hipStream_t stream) {
    const float* x      = (const float*)d_in[0];
    const float* h_ext  = (const float*)d_in[1];
    const float* c_ext  = (const float*)d_in[2];
    const float* grid_h = (const float*)d_in[3];
    const float* grid_c = (const float*)d_in[4];
    const float* W_hp   = (const float*)d_in[5];
    const float* b_hp   = (const float*)d_in[6];
    const float* W_cp   = (const float*)d_in[7];
    const float* b_cp   = (const float*)d_in[8];
    const float* W_ih   = (const float*)d_in[9];
    const float* W_hh   = (const float*)d_in[10];
    const float* b_ih   = (const float*)d_in[11];
    const float* b_hh   = (const float*)d_in[12];
    const float* W_out  = (const float*)d_in[13];
    const float* b_out  = (const float*)d_in[14];

    float* out = (float*)d_out;
    float* fh  = out + BATCH * 1;
    float* fc  = fh + SLOT;
    float* gh  = fc + SLOT;
    float* gc  = gh + (size_t)81 * SLOT;

    // new-path ws layout (fp32 gates_base):
    //  gates_base: 81 * B * 1024 f32   = 339,738,624 B
    //  CC:         81 * 1024*512 bf16  =  84,934,656 B
    //  pc_base:    81 * SLOT f32       =  84,934,656 B
    //  ph_base:    81 * SLOT f32       =  84,934,656 B
    const size_t gb_bytes = (size_t)81 * BATCH * 1024 * 4;
    const size_t cc_bytes = (size_t)81 * 1024 * 512 * 2;
    const size_t pb_bytes = (size_t)81 * SLOT * 4;
    const size_t need_new = gb_bytes + cc_bytes + 2 * pb_bytes;

    if (ws_size >= need_new) {
        float* gbase = (float*)d_ws;
        bf16_t* CC = (bf16_t*)((char*)d_ws + gb_bytes);
        float* pcb = (float*)((char*)d_ws + gb_bytes + cc_bytes);
        float* phb = (float*)((char*)d_ws + gb_bytes + cc_bytes + pb_bytes);

        baseproj_kernel<<<dim3(8, 2, 162), 256, 0, stream>>>(
            grid_h, grid_c, W_hp, W_cp, b_hp, b_cp, phb, pcb);
        compose_kernel<<<dim3(4, 8, 81), 256, 0, stream>>>(W_hh, W_hp, CC);
        gatesbase_kernel<<<dim3(8, 8, 81), 256, 0, stream>>>(
            phb, W_hh, W_ih, b_ih, b_hh, x, gbase);

        for (int d = 0; d <= 16; ++d) {
            const int i_lo = d > 8 ? d - 8 : 0;
            const int i_hi = d < 8 ? d : 8;
            const int nc = i_hi - i_lo + 1;
            FusedBatchArgs fa{};
            for (int s = 0; s < nc; ++s) {
                const int i = i_lo + s, j = d - i;
                const int k = i * 9 + j;
                const float *hl = nullptr, *cl = nullptr, *hu = nullptr, *cu = nullptr;
                if (i == 0 && j == 0)      { hl = h_ext; cl = c_ext; }
                else if (j > 0)            { hl = gh + (size_t)(k - 1) * SLOT;
                                             cl = gc + (size_t)(k - 1) * SLOT; }
                if (i > 0)                 { hu = gh + (size_t)(k - 9) * SLOT;
                                             cu = gc + (size_t)(k - 9) * SLOT; }
                fa.d[s] = { hl, cl, hu, cu,
                            gbase + (size_t)k * BATCH * 1024,
                            pcb + (size_t)k * SLOT,
                            CC + (size_t)k * 1024 * 512,
                            W_cp + (size_t)k * HID * W3,
                            gh + (size_t)k * SLOT,
                            gc + (size_t)k * SLOT };
            }
            fused_kernel<<<dim3(8, 8, nc), 256, 0, stream>>>(fa);
        }
    } else {
        // fallback: round-4 two-stage wavefront with 18 rotating slots
        float* ws = (float*)d_ws;
        for (int d = 0; d <= 16; ++d) {
            const int i_lo = d > 8 ? d - 8 : 0;
            const int i_hi = d < 8 ? d : 8;
            const int nc = i_hi - i_lo + 1;
            SegArgs base{}, inc{};
            CellBatchArgs ca{};
            int nb = 0, ni = 0;
            for (int s = 0; s < nc; ++s) {
                const int i = i_lo + s, j = d - i;
                const int k = i * 9 + j;
                float* oh = ws + (size_t)(2 * s) * SLOT;
                float* oc = oh + SLOT;
                const float* Wh = W_hp + (size_t)k * HID * W3;
                const float* Wc = W_cp + (size_t)k * HID * W3;
                base.d[nb++] = { grid_h + (size_t)k * SLOT, Wh, b_hp + (size_t)k * HID, oh, 512 };
                base.d[nb++] = { grid_c + (size_t)k * SLOT, Wc, b_cp + (size_t)k * HID, oc, 512 };
                if (i == 0 && j == 0) {
                    inc.d[ni++] = { h_ext, Wh, nullptr, oh, 0 };
                    inc.d[ni++] = { c_ext, Wc, nullptr, oc, 0 };
                } else if (j > 0) {
                    inc.d[ni++] = { gh + (size_t)(k - 1) * SLOT, Wh, nullptr, oh, 0 };
                    inc.d[ni++] = { gc + (size_t)(k - 1) * SLOT, Wc, nullptr, oc, 0 };
                }
                if (i > 0) {
                    inc.d[ni++] = { gh + (size_t)(k - 9) * SLOT, Wh, nullptr, oh, 256 };
                    inc.d[ni++] = { gc + (size_t)(k - 9) * SLOT, Wc, nullptr, oc, 256 };
                }
                ca.d[s] = { oh, oc,
                            W_hh + (size_t)k * 4 * HID * HID,
                            W_ih + (size_t)k * 4 * HID,
                            b_ih + (size_t)k * 4 * HID,
                            b_hh + (size_t)k * 4 * HID,
                            x + i * 9 + j,
                            gh + (size_t)k * SLOT,
                            gc + (size_t)k * SLOT };
            }
            projseg_kernel<<<dim3(8, 2, nb), 256, 0, stream>>>(base);
            projseg_kernel<<<dim3(8, 2, ni), 256, 0, stream>>>(inc);
            cell_kernel<<<dim3(8, 8, nc), 256, 0, stream>>>(ca);
        }
    }
    final_kernel<<<dim3(64), 256, 0, stream>>>(
        gh + (size_t)80 * SLOT, gc + (size_t)80 * SLOT,
        W_out, b_out, out, fh, fc);
}

// Round 6
// 1229.082 us; speedup vs baseline: 1.0099x; 1.0099x over previous
//
#include <hip/hip_runtime.h>
#include <math.h>

#define BATCH 1024
#define HID 256
#define W3 768
#define SLOT (BATCH * HID)

typedef __bf16 bf16_t;
typedef __bf16 bf16x8 __attribute__((ext_vector_type(8)));
typedef __bf16 bf16x4 __attribute__((ext_vector_type(4)));
typedef float f32x4 __attribute__((ext_vector_type(4)));

__device__ inline bf16x8 cvt8(const float4 a, const float4 b) {
    bf16x8 r;
    r[0] = (bf16_t)a.x; r[1] = (bf16_t)a.y; r[2] = (bf16_t)a.z; r[3] = (bf16_t)a.w;
    r[4] = (bf16_t)b.x; r[5] = (bf16_t)b.y; r[6] = (bf16_t)b.z; r[7] = (bf16_t)b.w;
    return r;
}
__device__ inline bf16x4 cvt4(const float4 a) {
    bf16x4 r;
    r[0] = (bf16_t)a.x; r[1] = (bf16_t)a.y; r[2] = (bf16_t)a.z; r[3] = (bf16_t)a.w;
    return r;
}

// ---------- P1: CC[k] = perm(Whh[k]) @ W_hp[k]  -> bf16 [1024][768] ----------
// CC row c' = by*128 + g*32 + du  <->  Whh row n4 = g*256 + by*32 + du
__global__ __launch_bounds__(256) void compose_kernel(
        const float* __restrict__ Whh, const float* __restrict__ Whp,
        bf16_t* __restrict__ CC) {
    __shared__ bf16_t As[128][40];
    __shared__ bf16_t Bs[128][40];
    const int k = blockIdx.z;
    const int t = threadIdx.x;
    const int lane = t & 63, wid = t >> 6;
    const int wm = wid & 1, wn = wid >> 1;
    const int ln = lane & 15, lh = lane >> 4;
    const int m0 = blockIdx.x * 128;   // 0..640 (6 tiles)
    const int by = blockIdx.y;         // 0..7
    const int sr = t >> 1, sq = (t & 1) * 16;
    const int g_r = sr >> 5, du_r = sr & 31;
    const float* arow = Whh + (size_t)k * 4 * HID * HID
                        + (size_t)(g_r * HID + by * 32 + du_r) * HID + sq;
    const float* wbase = Whp + (size_t)k * HID * W3;
    const int uu = t >> 3, mm0 = (t & 7) * 16;
    f32x4 acc[4][4] = {};
    for (int kb = 0; kb < 8; ++kb) {
        const float4 a0 = *(const float4*)(arow + kb * 32);
        const float4 a1 = *(const float4*)(arow + kb * 32 + 4);
        const float4 a2 = *(const float4*)(arow + kb * 32 + 8);
        const float4 a3 = *(const float4*)(arow + kb * 32 + 12);
        const float* bsrc = wbase + (size_t)(kb * 32 + uu) * W3 + m0 + mm0;
        const float4 v0 = *(const float4*)(bsrc);
        const float4 v1 = *(const float4*)(bsrc + 4);
        const float4 v2 = *(const float4*)(bsrc + 8);
        const float4 v3 = *(const float4*)(bsrc + 12);
        const bf16x8 av0 = cvt8(a0, a1), av1 = cvt8(a2, a3);
        const bf16x4 bq[4] = { cvt4(v0), cvt4(v1), cvt4(v2), cvt4(v3) };
        __syncthreads();
        *(bf16x8*)&As[sr][sq] = av0;
        *(bf16x8*)&As[sr][sq + 8] = av1;
        #pragma unroll
        for (int q = 0; q < 4; ++q)
            #pragma unroll
            for (int e = 0; e < 4; ++e)
                Bs[mm0 + q * 4 + e][uu] = bq[q][e];
        __syncthreads();
        bf16x8 af[4], bfv[4];
        #pragma unroll
        for (int mf = 0; mf < 4; ++mf)
            af[mf] = *(const bf16x8*)&As[wm * 64 + mf * 16 + ln][lh * 8];
        #pragma unroll
        for (int nf = 0; nf < 4; ++nf)
            bfv[nf] = *(const bf16x8*)&Bs[wn * 64 + nf * 16 + ln][lh * 8];
        #pragma unroll
        for (int mf = 0; mf < 4; ++mf)
            #pragma unroll
            for (int nf = 0; nf < 4; ++nf)
                acc[mf][nf] = __builtin_amdgcn_mfma_f32_16x16x32_bf16(
                    af[mf], bfv[nf], acc[mf][nf], 0, 0, 0);
    }
    bf16_t* outp = CC + (size_t)k * 1024 * W3;
    #pragma unroll
    for (int nf = 0; nf < 4; ++nf) {
        const int m = m0 + wn * 64 + nf * 16 + ln;
        #pragma unroll
        for (int mf = 0; mf < 4; ++mf)
            #pragma unroll
            for (int r = 0; r < 4; ++r) {
                const int c = by * 128 + wm * 64 + mf * 16 + lh * 4 + r;
                outp[(size_t)c * W3 + m] = (bf16_t)acc[mf][nf][r];
            }
    }
}

// ---------- P2: gvec[k][n4] = Whh[k][n4]·b_hp[k] + b_ih + b_hh (fp32) -------
__global__ __launch_bounds__(256) void gvec_kernel(
        const float* __restrict__ Whh, const float* __restrict__ bhp,
        const float* __restrict__ bih, const float* __restrict__ bhh,
        float* __restrict__ gvec) {
    const int k = blockIdx.x, t = threadIdx.x;
    __shared__ float bsm[HID];
    bsm[t] = bhp[(size_t)k * HID + t];
    __syncthreads();
    #pragma unroll
    for (int g = 0; g < 4; ++g) {
        const int n4 = g * HID + t;
        const float* wr = Whh + (size_t)k * 4 * HID * HID + (size_t)n4 * HID;
        float s = 0.f;
        for (int u = 0; u < HID; u += 4) {
            const float4 w = *(const float4*)(wr + u);
            s += w.x * bsm[u] + w.y * bsm[u + 1] + w.z * bsm[u + 2] + w.w * bsm[u + 3];
        }
        gvec[(size_t)k * 1024 + n4] = s + bih[(size_t)k * 1024 + n4]
                                        + bhh[(size_t)k * 1024 + n4];
    }
}

// ---------- wavefront: ONE launch per diagonal ----------
// Per cell: gates = [h_left|h_up|grid_h] @ CC^T (+gvec +x*Wih),
//           pc    = [c_left|c_up|grid_c] @ W_cp^T + b_cp,  then LSTM.
struct StageDesc {
    const float* hs0; const float* cs0;   // ko=0   (left) or null
    const float* hs1; const float* cs1;   // ko=256 (up) or null
    const float* hs2; const float* cs2;   // ko=512 (prev, always)
    const bf16_t* cc;                     // [1024][768] bf16, cell-layout rows
    const float* wcp;                     // W_cp[k] [256][768]
    const float* gvec;                    // [1024] natural n4 layout
    const float* wih;                     // [1024]
    const float* bcp;                     // [256]
    const float* xk;                      // x + k (stride 81)
    float* gh; float* gc;
};
struct StageArgs { StageDesc d[9]; };

__global__ __launch_bounds__(256) void stage_kernel(StageArgs args) {
    const StageDesc sd = args.d[blockIdx.z];
    __shared__ bf16_t A1[128][40];   // h segment tile
    __shared__ bf16_t A2[128][40];   // c segment tile
    __shared__ bf16_t B1[128][40];   // CC tile (128 gate-cols x 32k)
    __shared__ bf16_t B2[32][40];    // W_cp tile (32 units x 32k)
    const int t = threadIdx.x;
    const int lane = t & 63, wid = t >> 6;
    const int wm = wid & 1, wn = wid >> 1;
    const int ln = lane & 15, lh = lane >> 4;
    const int b0 = blockIdx.x * 128;
    const int by = blockIdx.y, u0 = by * 32;
    const int sr = t >> 1, sq = (t & 1) * 16;
    const int du2 = t >> 3, kk4 = (t & 7) * 4;

    const float* hs[3] = { sd.hs0, sd.hs1, sd.hs2 };
    const float* cs[3] = { sd.cs0, sd.cs1, sd.cs2 };

    f32x4 accg[4][4] = {};
    f32x4 accp[4] = {};

    for (int s = 0; s < 3; ++s) {
        if (!hs[s]) continue;
        const int ko = s * 256;
        const float* ha = hs[s] + (size_t)(b0 + sr) * HID + sq;
        const float* ca = cs[s] + (size_t)(b0 + sr) * HID + sq;
        const bf16_t* b1r = sd.cc + (size_t)(by * 128 + sr) * W3 + ko + sq;
        const float* b2r = sd.wcp + (size_t)(u0 + du2) * W3 + ko + kk4;
        for (int kb = 0; kb < 8; ++kb) {
            const float4 h0 = *(const float4*)(ha + kb * 32);
            const float4 h1 = *(const float4*)(ha + kb * 32 + 4);
            const float4 h2 = *(const float4*)(ha + kb * 32 + 8);
            const float4 h3 = *(const float4*)(ha + kb * 32 + 12);
            const float4 c0 = *(const float4*)(ca + kb * 32);
            const float4 c1 = *(const float4*)(ca + kb * 32 + 4);
            const float4 c2 = *(const float4*)(ca + kb * 32 + 8);
            const float4 c3 = *(const float4*)(ca + kb * 32 + 12);
            const bf16x8 w0 = *(const bf16x8*)(b1r + kb * 32);
            const bf16x8 w1 = *(const bf16x8*)(b1r + kb * 32 + 8);
            const float4 p0 = *(const float4*)(b2r + kb * 32);
            const bf16x8 hv0 = cvt8(h0, h1), hv1 = cvt8(h2, h3);
            const bf16x8 cv0 = cvt8(c0, c1), cv1 = cvt8(c2, c3);
            const bf16x4 pv = cvt4(p0);
            __syncthreads();
            *(bf16x8*)&A1[sr][sq] = hv0;
            *(bf16x8*)&A1[sr][sq + 8] = hv1;
            *(bf16x8*)&A2[sr][sq] = cv0;
            *(bf16x8*)&A2[sr][sq + 8] = cv1;
            *(bf16x8*)&B1[sr][sq] = w0;
            *(bf16x8*)&B1[sr][sq + 8] = w1;
            *(bf16x4*)&B2[du2][kk4] = pv;
            __syncthreads();
            bf16x8 af1[4], af2[4], bf1[4], bf2;
            #pragma unroll
            for (int mf = 0; mf < 4; ++mf) {
                af1[mf] = *(const bf16x8*)&A1[wm * 64 + mf * 16 + ln][lh * 8];
                af2[mf] = *(const bf16x8*)&A2[wm * 64 + mf * 16 + ln][lh * 8];
            }
            #pragma unroll
            for (int g = 0; g < 4; ++g)
                bf1[g] = *(const bf16x8*)&B1[g * 32 + wn * 16 + ln][lh * 8];
            bf2 = *(const bf16x8*)&B2[wn * 16 + ln][lh * 8];
            #pragma unroll
            for (int mf = 0; mf < 4; ++mf) {
                #pragma unroll
                for (int g = 0; g < 4; ++g)
                    accg[mf][g] = __builtin_amdgcn_mfma_f32_16x16x32_bf16(
                        af1[mf], bf1[g], accg[mf][g], 0, 0, 0);
                accp[mf] = __builtin_amdgcn_mfma_f32_16x16x32_bf16(
                    af2[mf], bf2, accp[mf], 0, 0, 0);
            }
        }
    }

    const int u = u0 + wn * 16 + ln;
    float wih[4], gv[4];
    #pragma unroll
    for (int g = 0; g < 4; ++g) {
        const int n4 = g * HID + u;
        wih[g] = sd.wih[n4];
        gv[g] = sd.gvec[n4];
    }
    const float bc = sd.bcp[u];
    #pragma unroll
    for (int mf = 0; mf < 4; ++mf)
        #pragma unroll
        for (int r = 0; r < 4; ++r) {
            const int b = b0 + wm * 64 + mf * 16 + lh * 4 + r;
            const float xv = sd.xk[(size_t)b * 81];
            const float gi = accg[mf][0][r] + gv[0] + xv * wih[0];
            const float gf = accg[mf][1][r] + gv[1] + xv * wih[1];
            const float gg = accg[mf][2][r] + gv[2] + xv * wih[2];
            const float go = accg[mf][3][r] + gv[3] + xv * wih[3];
            const float pc = accp[mf][r] + bc;
            const float i_ = 1.f / (1.f + expf(-gi));
            const float f_ = 1.f / (1.f + expf(-gf));
            const float o_ = 1.f / (1.f + expf(-go));
            const float g_ = tanhf(gg);
            const float cn = f_ * pc + i_ * g_;
            const float hn = o_ * tanhf(cn);
            sd.gh[(size_t)b * HID + u] = hn;
            sd.gc[(size_t)b * HID + u] = cn;
        }
}

__global__ __launch_bounds__(256) void final_kernel(
        const float* __restrict__ gh88, const float* __restrict__ gc88,
        const float* __restrict__ Wout, const float* __restrict__ bout,
        float* __restrict__ out, float* __restrict__ fh, float* __restrict__ fc) {
    const int tid = blockIdx.x * blockDim.x + threadIdx.x;
    const int nth = gridDim.x * blockDim.x;
    for (int idx = tid; idx < BATCH * HID; idx += nth) {
        fh[idx] = gh88[idx];
        fc[idx] = gc88[idx];
    }
    if (tid < BATCH) {
        float s = bout[0];
        for (int k = 0; k < HID; ++k) s += gh88[(size_t)tid * HID + k] * Wout[k];
        s = fmaxf(s, 0.f);
        out[tid] = 1.f / (1.f + expf(-s));
    }
}

// ---------- fallback (small ws): round-4 two-phase wavefront ----------
template<bool ATOMIC>
__device__ __forceinline__ void proj_core(
        const float* __restrict__ src, const float* __restrict__ W, int koff,
        const float* __restrict__ bias, float* __restrict__ out,
        bf16_t (*Asm)[40], bf16_t (*Bsm)[40]) {
    const int t = threadIdx.x;
    const int lane = t & 63, wid = t >> 6;
    const int wm = wid & 1, wn = wid >> 1;
    const int ln = lane & 15, lh = lane >> 4;
    const int b0 = blockIdx.x * 128, n0 = blockIdx.y * 128;
    const int sr = t >> 1, sq = (t & 1) * 16;
    const float* arow = src + (size_t)(b0 + sr) * HID + sq;
    const float* wrow = W + (size_t)(n0 + sr) * W3 + koff + sq;
    f32x4 acc[4][4] = {};
    for (int kb = 0; kb < 8; ++kb) {
        const float4 a0 = *(const float4*)(arow + kb * 32);
        const float4 a1 = *(const float4*)(arow + kb * 32 + 4);
        const float4 a2 = *(const float4*)(arow + kb * 32 + 8);
        const float4 a3 = *(const float4*)(arow + kb * 32 + 12);
        const float4 w0 = *(const float4*)(wrow + kb * 32);
        const float4 w1 = *(const float4*)(wrow + kb * 32 + 4);
        const float4 w2 = *(const float4*)(wrow + kb * 32 + 8);
        const float4 w3 = *(const float4*)(wrow + kb * 32 + 12);
        const bf16x8 av0 = cvt8(a0, a1), av1 = cvt8(a2, a3);
        const bf16x8 bv0 = cvt8(w0, w1), bv1 = cvt8(w2, w3);
        __syncthreads();
        *(bf16x8*)&Asm[sr][sq] = av0;
        *(bf16x8*)&Asm[sr][sq + 8] = av1;
        *(bf16x8*)&Bsm[sr][sq] = bv0;
        *(bf16x8*)&Bsm[sr][sq + 8] = bv1;
        __syncthreads();
        bf16x8 af[4], bfv[4];
        #pragma unroll
        for (int mf = 0; mf < 4; ++mf)
            af[mf] = *(const bf16x8*)&Asm[wm * 64 + mf * 16 + ln][lh * 8];
        #pragma unroll
        for (int nf = 0; nf < 4; ++nf)
            bfv[nf] = *(const bf16x8*)&Bsm[wn * 64 + nf * 16 + ln][lh * 8];
        #pragma unroll
        for (int mf = 0; mf < 4; ++mf)
            #pragma unroll
            for (int nf = 0; nf < 4; ++nf)
                acc[mf][nf] = __builtin_amdgcn_mfma_f32_16x16x32_bf16(
                    af[mf], bfv[nf], acc[mf][nf], 0, 0, 0);
    }
    #pragma unroll
    for (int nf = 0; nf < 4; ++nf) {
        const int n = n0 + wn * 64 + nf * 16 + ln;
        const float bn = ATOMIC ? 0.f : bias[n];
        #pragma unroll
        for (int mf = 0; mf < 4; ++mf)
            #pragma unroll
            for (int r = 0; r < 4; ++r) {
                const int b = b0 + wm * 64 + mf * 16 + lh * 4 + r;
                if (ATOMIC)
                    unsafeAtomicAdd(out + (size_t)b * HID + n, acc[mf][nf][r]);
                else
                    out[(size_t)b * HID + n] = acc[mf][nf][r] + bn;
            }
    }
}

struct SegDesc { const float* src; const float* W; const float* bias; float* out; int koff; };
struct SegArgs { SegDesc d[36]; };

__global__ __launch_bounds__(256) void projseg_kernel(SegArgs a) {
    __shared__ bf16_t As[128][40];
    __shared__ bf16_t Bs[128][40];
    const SegDesc d = a.d[blockIdx.z];
    if (d.bias) proj_core<false>(d.src, d.W, d.koff, d.bias, d.out, As, Bs);
    else        proj_core<true>(d.src, d.W, d.koff, nullptr, d.out, As, Bs);
}

struct CellDesc {
    const float* ph; const float* pc;
    const float* Whh; const float* Wih; const float* bih; const float* bhh;
    const float* xcol;
    float* gh; float* gc;
};
struct CellBatchArgs { CellDesc d[9]; };

__global__ __launch_bounds__(256) void cell_kernel(CellBatchArgs args) {
    const CellDesc cd = args.d[blockIdx.z];
    __shared__ bf16_t Psm[128][40];
    __shared__ bf16_t Wsm[128][40];
    const int t = threadIdx.x;
    const int lane = t & 63, wid = t >> 6;
    const int wm = wid & 1, wn = wid >> 1;
    const int ln = lane & 15, lh = lane >> 4;
    const int b0 = blockIdx.x * 128;
    const int u0 = blockIdx.y * 32;
    const int sr = t >> 1, sq = (t & 1) * 16;
    const float* prow = cd.ph + (size_t)(b0 + sr) * HID + sq;
    const int cg = sr >> 5, cdu = sr & 31;
    const float* wrow = cd.Whh + (size_t)(cg * HID + u0 + cdu) * HID + sq;
    f32x4 acc[4][4] = {};
    for (int kb = 0; kb < 8; ++kb) {
        const float4 p0 = *(const float4*)(prow + kb * 32);
        const float4 p1 = *(const float4*)(prow + kb * 32 + 4);
        const float4 p2 = *(const float4*)(prow + kb * 32 + 8);
        const float4 p3 = *(const float4*)(prow + kb * 32 + 12);
        const float4 w0 = *(const float4*)(wrow + kb * 32);
        const float4 w1 = *(const float4*)(wrow + kb * 32 + 4);
        const float4 w2 = *(const float4*)(wrow + kb * 32 + 8);
        const float4 w3 = *(const float4*)(wrow + kb * 32 + 12);
        const bf16x8 pv0 = cvt8(p0, p1), pv1 = cvt8(p2, p3);
        const bf16x8 wv0 = cvt8(w0, w1), wv1 = cvt8(w2, w3);
        __syncthreads();
        *(bf16x8*)&Psm[sr][sq] = pv0;
        *(bf16x8*)&Psm[sr][sq + 8] = pv1;
        *(bf16x8*)&Wsm[sr][sq] = wv0;
        *(bf16x8*)&Wsm[sr][sq + 8] = wv1;
        __syncthreads();
        bf16x8 af[4], bfr[4];
        #pragma unroll
        for (int mf = 0; mf < 4; ++mf)
            af[mf] = *(const bf16x8*)&Psm[wm * 64 + mf * 16 + ln][lh * 8];
        #pragma unroll
        for (int g = 0; g < 4; ++g)
            bfr[g] = *(const bf16x8*)&Wsm[g * 32 + wn * 16 + ln][lh * 8];
        #pragma unroll
        for (int mf = 0; mf < 4; ++mf)
            #pragma unroll
            for (int g = 0; g < 4; ++g)
                acc[mf][g] = __builtin_amdgcn_mfma_f32_16x16x32_bf16(
                    af[mf], bfr[g], acc[mf][g], 0, 0, 0);
    }
    const int u = u0 + wn * 16 + ln;
    float wih[4], bsum[4];
    #pragma unroll
    for (int g = 0; g < 4; ++g) {
        const int n = g * HID + u;
        wih[g] = cd.Wih[n];
        bsum[g] = cd.bih[n] + cd.bhh[n];
    }
    #pragma unroll
    for (int mf = 0; mf < 4; ++mf)
        #pragma unroll
        for (int r = 0; r < 4; ++r) {
            const int b = b0 + wm * 64 + mf * 16 + lh * 4 + r;
            const float xv = cd.xcol[(size_t)b * 81];
            const float gi = acc[mf][0][r] + xv * wih[0] + bsum[0];
            const float gf = acc[mf][1][r] + xv * wih[1] + bsum[1];
            const float gg = acc[mf][2][r] + xv * wih[2] + bsum[2];
            const float go = acc[mf][3][r] + xv * wih[3] + bsum[3];
            const float i_ = 1.f / (1.f + expf(-gi));
            const float f_ = 1.f / (1.f + expf(-gf));
            const float o_ = 1.f / (1.f + expf(-go));
            const float g_ = tanhf(gg);
            const float c0 = cd.pc[(size_t)b * HID + u];
            const float cn = f_ * c0 + i_ * g_;
            const float hn = o_ * tanhf(cn);
            cd.gh[(size_t)b * HID + u] = hn;
            cd.gc[(size_t)b * HID + u] = cn;
        }
}

extern "C" void kernel_launch(void* const* d_in, const int* in_sizes, int n_in,
                              void* d_out, int out_size, void* d_ws, size_t ws_size,
                              hipStream_t stream) {
    const float* x      = (const float*)d_in[0];
    const float* h_ext  = (const float*)d_in[1];
    const float* c_ext  = (const float*)d_in[2];
    const float* grid_h = (const float*)d_in[3];
    const float* grid_c = (const float*)d_in[4];
    const float* W_hp   = (const float*)d_in[5];
    const float* b_hp   = (const float*)d_in[6];
    const float* W_cp   = (const float*)d_in[7];
    const float* b_cp   = (const float*)d_in[8];
    const float* W_ih   = (const float*)d_in[9];
    const float* W_hh   = (const float*)d_in[10];
    const float* b_ih   = (const float*)d_in[11];
    const float* b_hh   = (const float*)d_in[12];
    const float* W_out  = (const float*)d_in[13];
    const float* b_out  = (const float*)d_in[14];

    float* out = (float*)d_out;
    float* fh  = out + BATCH * 1;
    float* fc  = fh + SLOT;
    float* gh  = fc + SLOT;
    float* gc  = gh + (size_t)81 * SLOT;

    const size_t cc_bytes = (size_t)81 * 1024 * W3 * 2;   // 127.4 MB
    const size_t gv_bytes = (size_t)81 * 1024 * 4;        // 0.33 MB

    if (ws_size >= cc_bytes + gv_bytes) {
        bf16_t* CC = (bf16_t*)d_ws;
        float* gvec = (float*)((char*)d_ws + cc_bytes);

        compose_kernel<<<dim3(6, 8, 81), 256, 0, stream>>>(W_hh, W_hp, CC);
        gvec_kernel<<<dim3(81), 256, 0, stream>>>(W_hh, b_hp, b_ih, b_hh, gvec);

        for (int d = 0; d <= 16; ++d) {
            const int i_lo = d > 8 ? d - 8 : 0;
            const int i_hi = d < 8 ? d : 8;
            const int nc = i_hi - i_lo + 1;
            StageArgs sa{};
            for (int s = 0; s < nc; ++s) {
                const int i = i_lo + s, j = d - i;
                const int k = i * 9 + j;
                const float *hl = nullptr, *cl = nullptr, *hu = nullptr, *cu = nullptr;
                if (i == 0 && j == 0)      { hl = h_ext; cl = c_ext; }
                else if (j > 0)            { hl = gh + (size_t)(k - 1) * SLOT;
                                             cl = gc + (size_t)(k - 1) * SLOT; }
                if (i > 0)                 { hu = gh + (size_t)(k - 9) * SLOT;
                                             cu = gc + (size_t)(k - 9) * SLOT; }
                sa.d[s] = { hl, cl, hu, cu,
                            grid_h + (size_t)k * SLOT, grid_c + (size_t)k * SLOT,
                            CC + (size_t)k * 1024 * W3,
                            W_cp + (size_t)k * HID * W3,
                            gvec + (size_t)k * 1024,
                            W_ih + (size_t)k * 1024,
                            b_cp + (size_t)k * HID,
                            x + k,
                            gh + (size_t)k * SLOT,
                            gc + (size_t)k * SLOT };
            }
            stage_kernel<<<dim3(8, 8, nc), 256, 0, stream>>>(sa);
        }
    } else {
        // fallback: two-phase wavefront with 18 rotating slots (needs 18.9 MB)
        float* ws = (float*)d_ws;
        for (int d = 0; d <= 16; ++d) {
            const int i_lo = d > 8 ? d - 8 : 0;
            const int i_hi = d < 8 ? d : 8;
            const int nc = i_hi - i_lo + 1;
            SegArgs base{}, inc{};
            CellBatchArgs ca{};
            int nb = 0, ni = 0;
            for (int s = 0; s < nc; ++s) {
                const int i = i_lo + s, j = d - i;
                const int k = i * 9 + j;
                float* oh = ws + (size_t)(2 * s) * SLOT;
                float* oc = oh + SLOT;
                const float* Wh = W_hp + (size_t)k * HID * W3;
                const float* Wc = W_cp + (size_t)k * HID * W3;
                base.d[nb++] = { grid_h + (size_t)k * SLOT, Wh, b_hp + (size_t)k * HID, oh, 512 };
                base.d[nb++] = { grid_c + (size_t)k * SLOT, Wc, b_cp + (size_t)k * HID, oc, 512 };
                if (i == 0 && j == 0) {
                    inc.d[ni++] = { h_ext, Wh, nullptr, oh, 0 };
                    inc.d[ni++] = { c_ext, Wc, nullptr, oc, 0 };
                } else if (j > 0) {
                    inc.d[ni++] = { gh + (size_t)(k - 1) * SLOT, Wh, nullptr, oh, 0 };
                    inc.d[ni++] = { gc + (size_t)(k - 1) * SLOT, Wc, nullptr, oc, 0 };
                }
                if (i > 0) {
                    inc.d[ni++] = { gh + (size_t)(k - 9) * SLOT, Wh, nullptr, oh, 256 };
                    inc.d[ni++] = { gc + (size_t)(k - 9) * SLOT, Wc, nullptr, oc, 256 };
                }
                ca.d[s] = { oh, oc,
                            W_hh + (size_t)k * 4 * HID * HID,
                            W_ih + (size_t)k * 4 * HID,
                            b_ih + (size_t)k * 4 * HID,
                            b_hh + (size_t)k * 4 * HID,
                            x + i * 9 + j,
                            gh + (size_t)k * SLOT,
                            gc + (size_t)k * SLOT };
            }
            projseg_kernel<<<dim3(8, 2, nb), 256, 0, stream>>>(base);
            projseg_kernel<<<dim3(8, 2, ni), 256, 0, stream>>>(inc);
            cell_kernel<<<dim3(8, 8, nc), 256, 0, stream>>>(ca);
        }
    }
    final_kernel<<<dim3(64), 256, 0, stream>>>(
        gh + (size_t)80 * SLOT, gc + (size_t)80 * SLOT,
        W_out, b_out, out, fh, fc);
}

// Round 7
// 1123.522 us; speedup vs baseline: 1.1047x; 1.0940x over previous
//
#include <hip/hip_runtime.h>
#include <math.h>

#define BATCH 1024
#define HID 256
#define W3 768
#define SLOT (BATCH * HID)

typedef __bf16 bf16_t;
typedef __bf16 bf16x8 __attribute__((ext_vector_type(8)));
typedef __bf16 bf16x4 __attribute__((ext_vector_type(4)));
typedef float f32x4 __attribute__((ext_vector_type(4)));

__device__ inline bf16x8 cvt8(const float4 a, const float4 b) {
    bf16x8 r;
    r[0] = (bf16_t)a.x; r[1] = (bf16_t)a.y; r[2] = (bf16_t)a.z; r[3] = (bf16_t)a.w;
    r[4] = (bf16_t)b.x; r[5] = (bf16_t)b.y; r[6] = (bf16_t)b.z; r[7] = (bf16_t)b.w;
    return r;
}
__device__ inline bf16x4 cvt4(const float4 a) {
    bf16x4 r;
    r[0] = (bf16_t)a.x; r[1] = (bf16_t)a.y; r[2] = (bf16_t)a.z; r[3] = (bf16_t)a.w;
    return r;
}

// ---------- prep: bf16 copies of W_cp and ext states ----------
__global__ __launch_bounds__(256) void prep_conv(
        const float* __restrict__ wcp, bf16_t* __restrict__ wcpb,
        const float* __restrict__ he, const float* __restrict__ ce,
        bf16_t* __restrict__ heb, bf16_t* __restrict__ ceb) {
    const size_t n1 = (size_t)81 * HID * W3;   // 15,925,248
    const size_t n2 = (size_t)SLOT;            // 262,144
    const size_t total4 = (n1 + 2 * n2) / 4;
    size_t tid = (size_t)blockIdx.x * 256 + threadIdx.x;
    const size_t nth = (size_t)gridDim.x * 256;
    for (size_t i4 = tid; i4 < total4; i4 += nth) {
        const size_t i = i4 * 4;
        const float* s; bf16_t* dst; size_t off;
        if (i < n1)            { s = wcp; dst = wcpb; off = i; }
        else if (i < n1 + n2)  { s = he;  dst = heb;  off = i - n1; }
        else                   { s = ce;  dst = ceb;  off = i - n1 - n2; }
        const float4 v = *(const float4*)(s + off);
        *(bf16x4*)(dst + off) = cvt4(v);
    }
}

// ---------- gvec[k][n4] = Whh[k][n4]·b_hp[k] + b_ih + b_hh ----------
__global__ __launch_bounds__(256) void gvec_kernel(
        const float* __restrict__ Whh, const float* __restrict__ bhp,
        const float* __restrict__ bih, const float* __restrict__ bhh,
        float* __restrict__ gvec) {
    const int k = blockIdx.x, t = threadIdx.x;
    __shared__ float bsm[HID];
    bsm[t] = bhp[(size_t)k * HID + t];
    __syncthreads();
    #pragma unroll
    for (int g = 0; g < 4; ++g) {
        const int n4 = g * HID + t;
        const float* wr = Whh + (size_t)k * 4 * HID * HID + (size_t)n4 * HID;
        float s = 0.f;
        for (int u = 0; u < HID; u += 4) {
            const float4 w = *(const float4*)(wr + u);
            s += w.x * bsm[u] + w.y * bsm[u + 1] + w.z * bsm[u + 2] + w.w * bsm[u + 3];
        }
        gvec[(size_t)k * 1024 + n4] = s + bih[(size_t)k * 1024 + n4]
                                        + bhh[(size_t)k * 1024 + n4];
    }
}

// ---------- CC[k] = perm(Whh[k]) @ W_hp[k] -> bf16 [1024][768] ----------
// CC row c' = by*128 + g*32 + du  <->  Whh row n4 = g*256 + by*32 + du
__global__ __launch_bounds__(256) void compose_kernel(
        const float* __restrict__ Whh, const float* __restrict__ Whp,
        bf16_t* __restrict__ CC) {
    __shared__ bf16_t As[128][40];
    __shared__ bf16_t Bs[128][40];
    const int k = blockIdx.z;
    const int t = threadIdx.x;
    const int lane = t & 63, wid = t >> 6;
    const int wm = wid & 1, wn = wid >> 1;
    const int ln = lane & 15, lh = lane >> 4;
    const int m0 = blockIdx.x * 128;
    const int by = blockIdx.y;
    const int sr = t >> 1, sq = (t & 1) * 16;
    const int g_r = sr >> 5, du_r = sr & 31;
    const float* arow = Whh + (size_t)k * 4 * HID * HID
                        + (size_t)(g_r * HID + by * 32 + du_r) * HID + sq;
    const float* wbase = Whp + (size_t)k * HID * W3;
    const int uu = t >> 3, mm0 = (t & 7) * 16;
    f32x4 acc[4][4] = {};
    for (int kb = 0; kb < 8; ++kb) {
        const float4 a0 = *(const float4*)(arow + kb * 32);
        const float4 a1 = *(const float4*)(arow + kb * 32 + 4);
        const float4 a2 = *(const float4*)(arow + kb * 32 + 8);
        const float4 a3 = *(const float4*)(arow + kb * 32 + 12);
        const float* bsrc = wbase + (size_t)(kb * 32 + uu) * W3 + m0 + mm0;
        const float4 v0 = *(const float4*)(bsrc);
        const float4 v1 = *(const float4*)(bsrc + 4);
        const float4 v2 = *(const float4*)(bsrc + 8);
        const float4 v3 = *(const float4*)(bsrc + 12);
        const bf16x8 av0 = cvt8(a0, a1), av1 = cvt8(a2, a3);
        const bf16x4 bq[4] = { cvt4(v0), cvt4(v1), cvt4(v2), cvt4(v3) };
        __syncthreads();
        *(bf16x8*)&As[sr][sq] = av0;
        *(bf16x8*)&As[sr][sq + 8] = av1;
        #pragma unroll
        for (int q = 0; q < 4; ++q)
            #pragma unroll
            for (int e = 0; e < 4; ++e)
                Bs[mm0 + q * 4 + e][uu] = bq[q][e];
        __syncthreads();
        bf16x8 af[4], bfv[4];
        #pragma unroll
        for (int mf = 0; mf < 4; ++mf)
            af[mf] = *(const bf16x8*)&As[wm * 64 + mf * 16 + ln][lh * 8];
        #pragma unroll
        for (int nf = 0; nf < 4; ++nf)
            bfv[nf] = *(const bf16x8*)&Bs[wn * 64 + nf * 16 + ln][lh * 8];
        #pragma unroll
        for (int mf = 0; mf < 4; ++mf)
            #pragma unroll
            for (int nf = 0; nf < 4; ++nf)
                acc[mf][nf] = __builtin_amdgcn_mfma_f32_16x16x32_bf16(
                    af[mf], bfv[nf], acc[mf][nf], 0, 0, 0);
    }
    bf16_t* outp = CC + (size_t)k * 1024 * W3;
    #pragma unroll
    for (int nf = 0; nf < 4; ++nf) {
        const int m = m0 + wn * 64 + nf * 16 + ln;
        #pragma unroll
        for (int mf = 0; mf < 4; ++mf)
            #pragma unroll
            for (int r = 0; r < 4; ++r) {
                const int c = by * 128 + wm * 64 + mf * 16 + lh * 4 + r;
                outp[(size_t)c * W3 + m] = (bf16_t)acc[mf][nf][r];
            }
    }
}

// ---------- prevgates: fully parallel over all 81 cells ----------
// gates_prev[k][b][c'] = grid_h[k]@CC[:,512:768]^T + gvec + x*Wih   (bf16)
// pc_prev[k][b][u]     = grid_c[k]@Wcpb[:,512:768]^T + b_cp         (bf16)
__global__ __launch_bounds__(256) void prevgates_kernel(
        const float* __restrict__ gridh, const float* __restrict__ gridc,
        const bf16_t* __restrict__ CC, const bf16_t* __restrict__ Wcpb,
        const float* __restrict__ gvec, const float* __restrict__ Wih,
        const float* __restrict__ bcp, const float* __restrict__ x,
        bf16_t* __restrict__ gp, bf16_t* __restrict__ pp) {
    const int k = blockIdx.z;
    __shared__ bf16_t A1[128][40];
    __shared__ bf16_t A2[128][40];
    __shared__ bf16_t B1[128][40];
    __shared__ bf16_t B2[32][40];
    const int t = threadIdx.x;
    const int lane = t & 63, wid = t >> 6;
    const int wm = wid & 1, wn = wid >> 1;
    const int ln = lane & 15, lh = lane >> 4;
    const int b0 = blockIdx.x * 128;
    const int by = blockIdx.y, u0 = by * 32;
    const int sr = t >> 1, sq = (t & 1) * 16;
    const int du2 = t >> 3, kk4 = (t & 7) * 4;

    const float* ha = gridh + (size_t)k * SLOT + (size_t)(b0 + sr) * HID + sq;
    const float* ca = gridc + (size_t)k * SLOT + (size_t)(b0 + sr) * HID + sq;
    const bf16_t* b1r = CC + (size_t)k * 1024 * W3 + (size_t)(by * 128 + sr) * W3 + 512 + sq;
    const bf16_t* b2r = Wcpb + (size_t)k * HID * W3 + (size_t)(u0 + du2) * W3 + 512 + kk4;

    f32x4 accg[4][4] = {};
    f32x4 accp[4] = {};
    for (int kb = 0; kb < 8; ++kb) {
        const float4 h0 = *(const float4*)(ha + kb * 32);
        const float4 h1 = *(const float4*)(ha + kb * 32 + 4);
        const float4 h2 = *(const float4*)(ha + kb * 32 + 8);
        const float4 h3 = *(const float4*)(ha + kb * 32 + 12);
        const float4 c0 = *(const float4*)(ca + kb * 32);
        const float4 c1 = *(const float4*)(ca + kb * 32 + 4);
        const float4 c2 = *(const float4*)(ca + kb * 32 + 8);
        const float4 c3 = *(const float4*)(ca + kb * 32 + 12);
        const bf16x8 w0 = *(const bf16x8*)(b1r + kb * 32);
        const bf16x8 w1 = *(const bf16x8*)(b1r + kb * 32 + 8);
        const bf16x4 p0 = *(const bf16x4*)(b2r + kb * 32);
        const bf16x8 hv0 = cvt8(h0, h1), hv1 = cvt8(h2, h3);
        const bf16x8 cv0 = cvt8(c0, c1), cv1 = cvt8(c2, c3);
        __syncthreads();
        *(bf16x8*)&A1[sr][sq] = hv0;  *(bf16x8*)&A1[sr][sq + 8] = hv1;
        *(bf16x8*)&A2[sr][sq] = cv0;  *(bf16x8*)&A2[sr][sq + 8] = cv1;
        *(bf16x8*)&B1[sr][sq] = w0;   *(bf16x8*)&B1[sr][sq + 8] = w1;
        *(bf16x4*)&B2[du2][kk4] = p0;
        __syncthreads();
        bf16x8 af1[4], af2[4], bf1[4], bf2;
        #pragma unroll
        for (int mf = 0; mf < 4; ++mf) {
            af1[mf] = *(const bf16x8*)&A1[wm * 64 + mf * 16 + ln][lh * 8];
            af2[mf] = *(const bf16x8*)&A2[wm * 64 + mf * 16 + ln][lh * 8];
        }
        #pragma unroll
        for (int g = 0; g < 4; ++g)
            bf1[g] = *(const bf16x8*)&B1[g * 32 + wn * 16 + ln][lh * 8];
        bf2 = *(const bf16x8*)&B2[wn * 16 + ln][lh * 8];
        #pragma unroll
        for (int mf = 0; mf < 4; ++mf) {
            #pragma unroll
            for (int g = 0; g < 4; ++g)
                accg[mf][g] = __builtin_amdgcn_mfma_f32_16x16x32_bf16(
                    af1[mf], bf1[g], accg[mf][g], 0, 0, 0);
            accp[mf] = __builtin_amdgcn_mfma_f32_16x16x32_bf16(
                af2[mf], bf2, accp[mf], 0, 0, 0);
        }
    }

    const int u = u0 + wn * 16 + ln;
    float wv[4], gv[4];
    #pragma unroll
    for (int g = 0; g < 4; ++g) {
        const int n4 = g * HID + u;
        wv[g] = Wih[(size_t)k * 1024 + n4];
        gv[g] = gvec[(size_t)k * 1024 + n4];
    }
    const float bc = bcp[(size_t)k * HID + u];
    bf16_t* gpk = gp + (size_t)k * BATCH * 1024;
    bf16_t* ppk = pp + (size_t)k * SLOT;
    #pragma unroll
    for (int mf = 0; mf < 4; ++mf)
        #pragma unroll
        for (int r = 0; r < 4; ++r) {
            const int b = b0 + wm * 64 + mf * 16 + lh * 4 + r;
            const float xv = x[(size_t)b * 81 + k];
            #pragma unroll
            for (int g = 0; g < 4; ++g)
                gpk[(size_t)b * 1024 + by * 128 + g * 32 + wn * 16 + ln] =
                    (bf16_t)(accg[mf][g][r] + gv[g] + xv * wv[g]);
            ppk[(size_t)b * HID + u] = (bf16_t)(accp[mf][r] + bc);
        }
}

// ---------- serial wavefront stage: K<=512, all-bf16 operands ----------
struct Stage2Desc {
    const bf16_t* hs0; const bf16_t* cs0;   // left seg (ko=0) or null
    const bf16_t* hs1; const bf16_t* cs1;   // up seg (ko=256) or null
    const bf16_t* cc;                       // CC[k] [1024][768]
    const bf16_t* wcpb;                     // [256][768]
    const bf16_t* gp;                       // gates_prev[k] [B][1024]
    const bf16_t* pp;                       // pc_prev[k] [B][256]
    float* gh; float* gc;
    bf16_t* ghb; bf16_t* gcb;
};
struct Stage2Args { Stage2Desc d[9]; };

__global__ __launch_bounds__(256) void stage2_kernel(Stage2Args args) {
    const Stage2Desc sd = args.d[blockIdx.z];
    __shared__ bf16_t A1[128][40];
    __shared__ bf16_t A2[128][40];
    __shared__ bf16_t B1[128][40];
    __shared__ bf16_t B2[32][40];
    const int t = threadIdx.x;
    const int lane = t & 63, wid = t >> 6;
    const int wm = wid & 1, wn = wid >> 1;
    const int ln = lane & 15, lh = lane >> 4;
    const int b0 = blockIdx.x * 128;
    const int by = blockIdx.y, u0 = by * 32;
    const int sr = t >> 1, sq = (t & 1) * 16;
    const int du2 = t >> 3, kk4 = (t & 7) * 4;

    const bf16_t* hs[2] = { sd.hs0, sd.hs1 };
    const bf16_t* cs[2] = { sd.cs0, sd.cs1 };

    f32x4 accg[4][4] = {};
    f32x4 accp[4] = {};

    for (int s = 0; s < 2; ++s) {
        if (!hs[s]) continue;
        const int ko = s * 256;
        const bf16_t* ha = hs[s] + (size_t)(b0 + sr) * HID + sq;
        const bf16_t* ca = cs[s] + (size_t)(b0 + sr) * HID + sq;
        const bf16_t* b1r = sd.cc + (size_t)(by * 128 + sr) * W3 + ko + sq;
        const bf16_t* b2r = sd.wcpb + (size_t)(u0 + du2) * W3 + ko + kk4;
        for (int kb = 0; kb < 8; ++kb) {
            const bf16x8 h0 = *(const bf16x8*)(ha + kb * 32);
            const bf16x8 h1 = *(const bf16x8*)(ha + kb * 32 + 8);
            const bf16x8 c0 = *(const bf16x8*)(ca + kb * 32);
            const bf16x8 c1 = *(const bf16x8*)(ca + kb * 32 + 8);
            const bf16x8 w0 = *(const bf16x8*)(b1r + kb * 32);
            const bf16x8 w1 = *(const bf16x8*)(b1r + kb * 32 + 8);
            const bf16x4 p0 = *(const bf16x4*)(b2r + kb * 32);
            __syncthreads();
            *(bf16x8*)&A1[sr][sq] = h0;  *(bf16x8*)&A1[sr][sq + 8] = h1;
            *(bf16x8*)&A2[sr][sq] = c0;  *(bf16x8*)&A2[sr][sq + 8] = c1;
            *(bf16x8*)&B1[sr][sq] = w0;  *(bf16x8*)&B1[sr][sq + 8] = w1;
            *(bf16x4*)&B2[du2][kk4] = p0;
            __syncthreads();
            bf16x8 af1[4], af2[4], bf1[4], bf2;
            #pragma unroll
            for (int mf = 0; mf < 4; ++mf) {
                af1[mf] = *(const bf16x8*)&A1[wm * 64 + mf * 16 + ln][lh * 8];
                af2[mf] = *(const bf16x8*)&A2[wm * 64 + mf * 16 + ln][lh * 8];
            }
            #pragma unroll
            for (int g = 0; g < 4; ++g)
                bf1[g] = *(const bf16x8*)&B1[g * 32 + wn * 16 + ln][lh * 8];
            bf2 = *(const bf16x8*)&B2[wn * 16 + ln][lh * 8];
            #pragma unroll
            for (int mf = 0; mf < 4; ++mf) {
                #pragma unroll
                for (int g = 0; g < 4; ++g)
                    accg[mf][g] = __builtin_amdgcn_mfma_f32_16x16x32_bf16(
                        af1[mf], bf1[g], accg[mf][g], 0, 0, 0);
                accp[mf] = __builtin_amdgcn_mfma_f32_16x16x32_bf16(
                    af2[mf], bf2, accp[mf], 0, 0, 0);
            }
        }
    }

    const int u = u0 + wn * 16 + ln;
    #pragma unroll
    for (int mf = 0; mf < 4; ++mf)
        #pragma unroll
        for (int r = 0; r < 4; ++r) {
            const int b = b0 + wm * 64 + mf * 16 + lh * 4 + r;
            const bf16_t* gpr = sd.gp + (size_t)b * 1024 + by * 128 + wn * 16 + ln;
            const float gi = accg[mf][0][r] + (float)gpr[0];
            const float gf = accg[mf][1][r] + (float)gpr[32];
            const float gg = accg[mf][2][r] + (float)gpr[64];
            const float go = accg[mf][3][r] + (float)gpr[96];
            const float pc = accp[mf][r] + (float)sd.pp[(size_t)b * HID + u];
            const float i_ = 1.f / (1.f + expf(-gi));
            const float f_ = 1.f / (1.f + expf(-gf));
            const float o_ = 1.f / (1.f + expf(-go));
            const float g_ = tanhf(gg);
            const float cn = f_ * pc + i_ * g_;
            const float hn = o_ * tanhf(cn);
            sd.gh[(size_t)b * HID + u] = hn;
            sd.gc[(size_t)b * HID + u] = cn;
            sd.ghb[(size_t)b * HID + u] = (bf16_t)hn;
            sd.gcb[(size_t)b * HID + u] = (bf16_t)cn;
        }
}

__global__ __launch_bounds__(256) void final_kernel(
        const float* __restrict__ gh88, const float* __restrict__ gc88,
        const float* __restrict__ Wout, const float* __restrict__ bout,
        float* __restrict__ out, float* __restrict__ fh, float* __restrict__ fc) {
    const int tid = blockIdx.x * blockDim.x + threadIdx.x;
    const int nth = gridDim.x * blockDim.x;
    for (int idx = tid; idx < BATCH * HID; idx += nth) {
        fh[idx] = gh88[idx];
        fc[idx] = gc88[idx];
    }
    if (tid < BATCH) {
        float s = bout[0];
        for (int k = 0; k < HID; ++k) s += gh88[(size_t)tid * HID + k] * Wout[k];
        s = fmaxf(s, 0.f);
        out[tid] = 1.f / (1.f + expf(-s));
    }
}

// ---------- fallback (small ws): two-phase wavefront ----------
template<bool ATOMIC>
__device__ __forceinline__ void proj_core(
        const float* __restrict__ src, const float* __restrict__ W, int koff,
        const float* __restrict__ bias, float* __restrict__ out,
        bf16_t (*Asm)[40], bf16_t (*Bsm)[40]) {
    const int t = threadIdx.x;
    const int lane = t & 63, wid = t >> 6;
    const int wm = wid & 1, wn = wid >> 1;
    const int ln = lane & 15, lh = lane >> 4;
    const int b0 = blockIdx.x * 128, n0 = blockIdx.y * 128;
    const int sr = t >> 1, sq = (t & 1) * 16;
    const float* arow = src + (size_t)(b0 + sr) * HID + sq;
    const float* wrow = W + (size_t)(n0 + sr) * W3 + koff + sq;
    f32x4 acc[4][4] = {};
    for (int kb = 0; kb < 8; ++kb) {
        const float4 a0 = *(const float4*)(arow + kb * 32);
        const float4 a1 = *(const float4*)(arow + kb * 32 + 4);
        const float4 a2 = *(const float4*)(arow + kb * 32 + 8);
        const float4 a3 = *(const float4*)(arow + kb * 32 + 12);
        const float4 w0 = *(const float4*)(wrow + kb * 32);
        const float4 w1 = *(const float4*)(wrow + kb * 32 + 4);
        const float4 w2 = *(const float4*)(wrow + kb * 32 + 8);
        const float4 w3 = *(const float4*)(wrow + kb * 32 + 12);
        const bf16x8 av0 = cvt8(a0, a1), av1 = cvt8(a2, a3);
        const bf16x8 bv0 = cvt8(w0, w1), bv1 = cvt8(w2, w3);
        __syncthreads();
        *(bf16x8*)&Asm[sr][sq] = av0;
        *(bf16x8*)&Asm[sr][sq + 8] = av1;
        *(bf16x8*)&Bsm[sr][sq] = bv0;
        *(bf16x8*)&Bsm[sr][sq + 8] = bv1;
        __syncthreads();
        bf16x8 af[4], bfv[4];
        #pragma unroll
        for (int mf = 0; mf < 4; ++mf)
            af[mf] = *(const bf16x8*)&Asm[wm * 64 + mf * 16 + ln][lh * 8];
        #pragma unroll
        for (int nf = 0; nf < 4; ++nf)
            bfv[nf] = *(const bf16x8*)&Bsm[wn * 64 + nf * 16 + ln][lh * 8];
        #pragma unroll
        for (int mf = 0; mf < 4; ++mf)
            #pragma unroll
            for (int nf = 0; nf < 4; ++nf)
                acc[mf][nf] = __builtin_amdgcn_mfma_f32_16x16x32_bf16(
                    af[mf], bfv[nf], acc[mf][nf], 0, 0, 0);
    }
    #pragma unroll
    for (int nf = 0; nf < 4; ++nf) {
        const int n = n0 + wn * 64 + nf * 16 + ln;
        const float bn = ATOMIC ? 0.f : bias[n];
        #pragma unroll
        for (int mf = 0; mf < 4; ++mf)
            #pragma unroll
            for (int r = 0; r < 4; ++r) {
                const int b = b0 + wm * 64 + mf * 16 + lh * 4 + r;
                if (ATOMIC)
                    unsafeAtomicAdd(out + (size_t)b * HID + n, acc[mf][nf][r]);
                else
                    out[(size_t)b * HID + n] = acc[mf][nf][r] + bn;
            }
    }
}

struct SegDesc { const float* src; const float* W; const float* bias; float* out; int koff; };
struct SegArgs { SegDesc d[36]; };

__global__ __launch_bounds__(256) void projseg_kernel(SegArgs a) {
    __shared__ bf16_t As[128][40];
    __shared__ bf16_t Bs[128][40];
    const SegDesc d = a.d[blockIdx.z];
    if (d.bias) proj_core<false>(d.src, d.W, d.koff, d.bias, d.out, As, Bs);
    else        proj_core<true>(d.src, d.W, d.koff, nullptr, d.out, As, Bs);
}

struct CellDesc {
    const float* ph; const float* pc;
    const float* Whh; const float* Wih; const float* bih; const float* bhh;
    const float* xcol;
    float* gh; float* gc;
};
struct CellBatchArgs { CellDesc d[9]; };

__global__ __launch_bounds__(256) void cell_kernel(CellBatchArgs args) {
    const CellDesc cd = args.d[blockIdx.z];
    __shared__ bf16_t Psm[128][40];
    __shared__ bf16_t Wsm[128][40];
    const int t = threadIdx.x;
    const int lane = t & 63, wid = t >> 6;
    const int wm = wid & 1, wn = wid >> 1;
    const int ln = lane & 15, lh = lane >> 4;
    const int b0 = blockIdx.x * 128;
    const int u0 = blockIdx.y * 32;
    const int sr = t >> 1, sq = (t & 1) * 16;
    const float* prow = cd.ph + (size_t)(b0 + sr) * HID + sq;
    const int cg = sr >> 5, cdu = sr & 31;
    const float* wrow = cd.Whh + (size_t)(cg * HID + u0 + cdu) * HID + sq;
    f32x4 acc[4][4] = {};
    for (int kb = 0; kb < 8; ++kb) {
        const float4 p0 = *(const float4*)(prow + kb * 32);
        const float4 p1 = *(const float4*)(prow + kb * 32 + 4);
        const float4 p2 = *(const float4*)(prow + kb * 32 + 8);
        const float4 p3 = *(const float4*)(prow + kb * 32 + 12);
        const float4 w0 = *(const float4*)(wrow + kb * 32);
        const float4 w1 = *(const float4*)(wrow + kb * 32 + 4);
        const float4 w2 = *(const float4*)(wrow + kb * 32 + 8);
        const float4 w3 = *(const float4*)(wrow + kb * 32 + 12);
        const bf16x8 pv0 = cvt8(p0, p1), pv1 = cvt8(p2, p3);
        const bf16x8 wv0 = cvt8(w0, w1), wv1 = cvt8(w2, w3);
        __syncthreads();
        *(bf16x8*)&Psm[sr][sq] = pv0;
        *(bf16x8*)&Psm[sr][sq + 8] = pv1;
        *(bf16x8*)&Wsm[sr][sq] = wv0;
        *(bf16x8*)&Wsm[sr][sq + 8] = wv1;
        __syncthreads();
        bf16x8 af[4], bfr[4];
        #pragma unroll
        for (int mf = 0; mf < 4; ++mf)
            af[mf] = *(const bf16x8*)&Psm[wm * 64 + mf * 16 + ln][lh * 8];
        #pragma unroll
        for (int g = 0; g < 4; ++g)
            bfr[g] = *(const bf16x8*)&Wsm[g * 32 + wn * 16 + ln][lh * 8];
        #pragma unroll
        for (int mf = 0; mf < 4; ++mf)
            #pragma unroll
            for (int g = 0; g < 4; ++g)
                acc[mf][g] = __builtin_amdgcn_mfma_f32_16x16x32_bf16(
                    af[mf], bfr[g], acc[mf][g], 0, 0, 0);
    }
    const int u = u0 + wn * 16 + ln;
    float wih[4], bsum[4];
    #pragma unroll
    for (int g = 0; g < 4; ++g) {
        const int n = g * HID + u;
        wih[g] = cd.Wih[n];
        bsum[g] = cd.bih[n] + cd.bhh[n];
    }
    #pragma unroll
    for (int mf = 0; mf < 4; ++mf)
        #pragma unroll
        for (int r = 0; r < 4; ++r) {
            const int b = b0 + wm * 64 + mf * 16 + lh * 4 + r;
            const float xv = cd.xcol[(size_t)b * 81];
            const float gi = acc[mf][0][r] + xv * wih[0] + bsum[0];
            const float gf = acc[mf][1][r] + xv * wih[1] + bsum[1];
            const float gg = acc[mf][2][r] + xv * wih[2] + bsum[2];
            const float go = acc[mf][3][r] + xv * wih[3] + bsum[3];
            const float i_ = 1.f / (1.f + expf(-gi));
            const float f_ = 1.f / (1.f + expf(-gf));
            const float o_ = 1.f / (1.f + expf(-go));
            const float g_ = tanhf(gg);
            const float c0 = cd.pc[(size_t)b * HID + u];
            const float cn = f_ * c0 + i_ * g_;
            const float hn = o_ * tanhf(cn);
            cd.gh[(size_t)b * HID + u] = hn;
            cd.gc[(size_t)b * HID + u] = cn;
        }
}

extern "C" void kernel_launch(void* const* d_in, const int* in_sizes, int n_in,
                              void* d_out, int out_size, void* d_ws, size_t ws_size,
                              hipStream_t stream) {
    const float* x      = (const float*)d_in[0];
    const float* h_ext  = (const float*)d_in[1];
    const float* c_ext  = (const float*)d_in[2];
    const float* grid_h = (const float*)d_in[3];
    const float* grid_c = (const float*)d_in[4];
    const float* W_hp   = (const float*)d_in[5];
    const float* b_hp   = (const float*)d_in[6];
    const float* W_cp   = (const float*)d_in[7];
    const float* b_cp   = (const float*)d_in[8];
    const float* W_ih   = (const float*)d_in[9];
    const float* W_hh   = (const float*)d_in[10];
    const float* b_ih   = (const float*)d_in[11];
    const float* b_hh   = (const float*)d_in[12];
    const float* W_out  = (const float*)d_in[13];
    const float* b_out  = (const float*)d_in[14];

    float* out = (float*)d_out;
    float* fh  = out + BATCH * 1;
    float* fc  = fh + SLOT;
    float* gh  = fc + SLOT;
    float* gc  = gh + (size_t)81 * SLOT;

    const size_t cc_b  = (size_t)81 * 1024 * W3 * 2;   // 127,401,984
    const size_t wcp_b = (size_t)81 * HID * W3 * 2;    //  31,850,496
    const size_t gp_b  = (size_t)81 * BATCH * 1024 * 2;// 169,869,312
    const size_t pp_b  = (size_t)81 * SLOT * 2;        //  42,467,328
    const size_t st_b  = (size_t)81 * SLOT * 2;        //  42,467,328
    const size_t ext_b = (size_t)SLOT * 2;             //     524,288
    const size_t gv_b  = (size_t)81 * 1024 * 4;        //     331,776
    const size_t need = cc_b + wcp_b + gp_b + pp_b + 2 * st_b + 2 * ext_b + gv_b;

    if (ws_size >= need) {
        char* p = (char*)d_ws;
        bf16_t* CC   = (bf16_t*)p; p += cc_b;
        bf16_t* Wcpb = (bf16_t*)p; p += wcp_b;
        bf16_t* GP   = (bf16_t*)p; p += gp_b;
        bf16_t* PP   = (bf16_t*)p; p += pp_b;
        bf16_t* GHB  = (bf16_t*)p; p += st_b;
        bf16_t* GCB  = (bf16_t*)p; p += st_b;
        bf16_t* HEB  = (bf16_t*)p; p += ext_b;
        bf16_t* CEB  = (bf16_t*)p; p += ext_b;
        float*  gvec = (float*)p;

        prep_conv<<<dim3(2048), 256, 0, stream>>>(W_cp, Wcpb, h_ext, c_ext, HEB, CEB);
        gvec_kernel<<<dim3(81), 256, 0, stream>>>(W_hh, b_hp, b_ih, b_hh, gvec);
        compose_kernel<<<dim3(6, 8, 81), 256, 0, stream>>>(W_hh, W_hp, CC);
        prevgates_kernel<<<dim3(8, 8, 81), 256, 0, stream>>>(
            grid_h, grid_c, CC, Wcpb, gvec, W_ih, b_cp, x, GP, PP);

        for (int d = 0; d <= 16; ++d) {
            const int i_lo = d > 8 ? d - 8 : 0;
            const int i_hi = d < 8 ? d : 8;
            const int nc = i_hi - i_lo + 1;
            Stage2Args sa{};
            for (int s = 0; s < nc; ++s) {
                const int i = i_lo + s, j = d - i;
                const int k = i * 9 + j;
                const bf16_t *hl = nullptr, *cl = nullptr, *hu = nullptr, *cu = nullptr;
                if (i == 0 && j == 0)      { hl = HEB; cl = CEB; }
                else if (j > 0)            { hl = GHB + (size_t)(k - 1) * SLOT;
                                             cl = GCB + (size_t)(k - 1) * SLOT; }
                if (i > 0)                 { hu = GHB + (size_t)(k - 9) * SLOT;
                                             cu = GCB + (size_t)(k - 9) * SLOT; }
                sa.d[s] = { hl, cl, hu, cu,
                            CC + (size_t)k * 1024 * W3,
                            Wcpb + (size_t)k * HID * W3,
                            GP + (size_t)k * BATCH * 1024,
                            PP + (size_t)k * SLOT,
                            gh + (size_t)k * SLOT, gc + (size_t)k * SLOT,
                            GHB + (size_t)k * SLOT, GCB + (size_t)k * SLOT };
            }
            stage2_kernel<<<dim3(8, 8, nc), 256, 0, stream>>>(sa);
        }
    } else {
        // fallback: two-phase wavefront with 18 rotating slots (needs 18.9 MB)
        float* ws = (float*)d_ws;
        for (int d = 0; d <= 16; ++d) {
            const int i_lo = d > 8 ? d - 8 : 0;
            const int i_hi = d < 8 ? d : 8;
            const int nc = i_hi - i_lo + 1;
            SegArgs base{}, inc{};
            CellBatchArgs ca{};
            int nb = 0, ni = 0;
            for (int s = 0; s < nc; ++s) {
                const int i = i_lo + s, j = d - i;
                const int k = i * 9 + j;
                float* oh = ws + (size_t)(2 * s) * SLOT;
                float* oc = oh + SLOT;
                const float* Wh = W_hp + (size_t)k * HID * W3;
                const float* Wc = W_cp + (size_t)k * HID * W3;
                base.d[nb++] = { grid_h + (size_t)k * SLOT, Wh, b_hp + (size_t)k * HID, oh, 512 };
                base.d[nb++] = { grid_c + (size_t)k * SLOT, Wc, b_cp + (size_t)k * HID, oc, 512 };
                if (i == 0 && j == 0) {
                    inc.d[ni++] = { h_ext, Wh, nullptr, oh, 0 };
                    inc.d[ni++] = { c_ext, Wc, nullptr, oc, 0 };
                } else if (j > 0) {
                    inc.d[ni++] = { gh + (size_t)(k - 1) * SLOT, Wh, nullptr, oh, 0 };
                    inc.d[ni++] = { gc + (size_t)(k - 1) * SLOT, Wc, nullptr, oc, 0 };
                }
                if (i > 0) {
                    inc.d[ni++] = { gh + (size_t)(k - 9) * SLOT, Wh, nullptr, oh, 256 };
                    inc.d[ni++] = { gc + (size_t)(k - 9) * SLOT, Wc, nullptr, oc, 256 };
                }
                ca.d[s] = { oh, oc,
                            W_hh + (size_t)k * 4 * HID * HID,
                            W_ih + (size_t)k * 4 * HID,
                            b_ih + (size_t)k * 4 * HID,
                            b_hh + (size_t)k * 4 * HID,
                            x + i * 9 + j,
                            gh + (size_t)k * SLOT,
                            gc + (size_t)k * SLOT };
            }
            projseg_kernel<<<dim3(8, 2, nb), 256, 0, stream>>>(base);
            projseg_kernel<<<dim3(8, 2, ni), 256, 0, stream>>>(inc);
            cell_kernel<<<dim3(8, 8, nc), 256, 0, stream>>>(ca);
        }
    }
    final_kernel<<<dim3(64), 256, 0, stream>>>(
        gh + (size_t)80 * SLOT, gc + (size_t)80 * SLOT,
        W_out, b_out, out, fh, fc);
}